// Round 11
// baseline (1764.978 us; speedup 1.0000x reference)
//
#include <hip/hip_runtime.h>

// ---------------------------------------------------------------------------
// VQ-VAE forward, round 11: conv2/conv3 co x8 + explicit x prefetch
// (register double-buffer) to cover L1 latency. Encoder bitwise-identical.
// Numerics contract (validated r3-r10): every reference op = fl32(f64-exact
// op on fp32 operands); d in fp32; first-index argmin; f64 assoc freedom OK.
//
// d_out (float32): recon[786432] | commit_loss[1] | indices[16384]
#define OFF_A     ((size_t)0)          // h1p / Ap / d2p
#define OFF_BINFO ((size_t)8388608)
#define OFF_B     ((size_t)34611200)   // h2p / qbufp
#define OFF_C     ((size_t)43532288)   // xpad / h3 / d1p
#define OFF_D     ((size_t)52453376)   // zf
#define OFF_E     ((size_t)69230592)   // Bp / PC
#define OFF_ZN    ((size_t)81813504)
#define OFF_CN    ((size_t)81879040)
#define OFF_IDX   ((size_t)81911808)
#define OFF_ACC   ((size_t)81977344)
#define OFF_WR2   ((size_t)81977600)
#define OFF_WR3   ((size_t)83026176)
#define OFF_QWT   ((size_t)83050752)
#define OFF_WD2   ((size_t)83181824)   // f64 conv2 weights, 2 MB
#define OFF_WD3   ((size_t)85278976)   // f64 conv3 weights, 1.18 MB
#define OFF_WD1   ((size_t)86458624)   // f64 conv1 weights, 48 KB

#define VQ_MARGIN 1.2e-4f
#define LDSS 40

typedef __attribute__((ext_vector_type(8))) _Float16 f16x8;
typedef __attribute__((ext_vector_type(4))) float f32x4;

// ---------- helpers ----------
__device__ __forceinline__ unsigned fkey(float f) {
  unsigned u = __float_as_uint(f);
  return (u & 0x80000000u) ? ~u : (u | 0x80000000u);
}
__device__ __forceinline__ float funkey(unsigned k) {
  unsigned u = (k & 0x80000000u) ? (k ^ 0x80000000u) : ~k;
  return __uint_as_float(u);
}
__device__ __forceinline__ void padzero_img(float* base, int S, int t) {
  for (int e = t; e < 4 * S - 4; e += 256) {
    int rr, cc;
    if (e < S) { rr = 0; cc = e; }
    else if (e < 2 * S) { rr = S - 1; cc = e - S; }
    else { rr = ((e - 2 * S) >> 1) + 1; cc = (e & 1) ? (S - 1) : 0; }
    base[rr * S + cc] = 0.0f;
  }
}

// ---------- ONE prep kernel: weight reshapes/widens + encoder pad zeros ----------
__global__ __launch_bounds__(256) void prep_k(
    const float* __restrict__ dtw2, float* __restrict__ wr2,
    const float* __restrict__ dtw3, float* __restrict__ wr3,
    const float* __restrict__ qw,   float* __restrict__ qwT,
    const float* __restrict__ ew2,  double* __restrict__ wd2,
    const float* __restrict__ ew3,  double* __restrict__ wd3,
    const float* __restrict__ ew1,  double* __restrict__ wd1,
    float* __restrict__ xpad, float* __restrict__ h1p, float* __restrict__ h2p) {
  int b = blockIdx.x, t = threadIdx.x;
  if (b < 256) {
    int tid = b * 256 + t;
    int ci = tid & 127, co = (tid >> 7) & 127, cls = tid >> 14;
    int kh0 = 1 - (cls >> 1), kw0 = 1 - (cls & 1);
    const float* s = dtw2 + ((size_t)ci * 128 + co) * 16;
    float* d = wr2 + (size_t)tid * 4;
    d[0] = s[kh0 * 4 + kw0];       d[1] = s[kh0 * 4 + kw0 + 2];
    d[2] = s[(kh0 + 2) * 4 + kw0]; d[3] = s[(kh0 + 2) * 4 + kw0 + 2];
  } else if (b < 262) {
    int tid = (b - 256) * 256 + t;
    if (tid < 1536) {
      int ci = tid & 127, co = (tid >> 7) % 3, cls = tid / 384;
      int kh0 = 1 - (cls >> 1), kw0 = 1 - (cls & 1);
      const float* s = dtw3 + ((size_t)ci * 3 + co) * 16;
      float* d = wr3 + (size_t)tid * 4;
      d[0] = s[kh0 * 4 + kw0];       d[1] = s[kh0 * 4 + kw0 + 2];
      d[2] = s[(kh0 + 2) * 4 + kw0]; d[3] = s[(kh0 + 2) * 4 + kw0 + 2];
    }
  } else if (b < 390) {
    int tid = (b - 262) * 256 + t;
    int co = tid & 255, ci = tid >> 8;
    qwT[(size_t)ci * 256 + co] = qw[(size_t)co * 128 + ci];
  } else if (b < 1414) {
    int tid = (b - 390) * 256 + t;
    wd2[tid] = (double)ew2[tid];
  } else if (b < 1990) {
    int tid = (b - 1414) * 256 + t;
    wd3[tid] = (double)ew3[tid];
  } else if (b < 2014) {
    int tid = (b - 1990) * 256 + t;
    wd1[tid] = (double)ew1[tid];
  } else if (b < 2026) {
    padzero_img(xpad + (size_t)(b - 2014) * 66564, 258, t);
  } else if (b < 2538) {
    padzero_img(h1p + (size_t)(b - 2026) * 16900, 130, t);
  } else {
    padzero_img(h2p + (size_t)(b - 2538) * 4356, 66, t);
  }
}

// ---------- pad-copy x into [4][3][258][258] ----------
__global__ __launch_bounds__(256) void padx_k(const float* __restrict__ x,
                                              float* __restrict__ xp) {
  int tid = blockIdx.x * 256 + threadIdx.x;
  int wo = tid & 255, ho = (tid >> 8) & 255, c = tid >> 16;
  xp[((size_t)c * 258 + ho + 1) * 258 + wo + 1] = x[tid];
}

// ---------- enc conv1: k=4 s=2 + ReLU, 3ci, co x4, f64 weights ----------
__global__ __launch_bounds__(256) void conv1_k(
    const float* __restrict__ xp, const double* __restrict__ wd,
    const float* __restrict__ bias, float* __restrict__ h1p) {
  int b = blockIdx.x;
  int chunk = b & 63, cog = (b >> 6) & 31, n = b >> 11;
  int t = threadIdx.x;
  int wo = t & 127, ho = chunk * 2 + (t >> 7);
  int co0 = cog * 4;
  const float* xb = xp + (size_t)n * 3 * 66564 + (size_t)(2 * ho) * 258 + 2 * wo;
  double acc[4] = {0.0, 0.0, 0.0, 0.0};
  for (int ci = 0; ci < 3; ++ci) {
    const float* xc = xb + (size_t)ci * 66564;
    double xd[16];
#pragma unroll
    for (int kh = 0; kh < 4; ++kh)
#pragma unroll
      for (int kw = 0; kw < 4; ++kw) xd[kh * 4 + kw] = (double)xc[kh * 258 + kw];
#pragma unroll
    for (int cc = 0; cc < 4; ++cc) {
      const double* wp = wd + (size_t)(co0 + cc) * 48 + ci * 16;
#pragma unroll
      for (int tp = 0; tp < 16; ++tp)
        acc[cc] = fma(xd[tp], wp[tp], acc[cc]);
    }
  }
#pragma unroll
  for (int cc = 0; cc < 4; ++cc) {
    float r = (float)((double)bias[co0 + cc] + acc[cc]);
    h1p[(((size_t)n * 128 + co0 + cc) * 130 + ho + 1) * 130 + wo + 1] = fmaxf(r, 0.0f);
  }
}

// ---------- enc conv2: k=4 s=2 + ReLU, 128ci, co x8, f64 w, x prefetch ----------
__global__ __launch_bounds__(256) void conv2_k(
    const float* __restrict__ h1p, const double* __restrict__ wd,
    const float* __restrict__ bias, float* __restrict__ h2p) {
  int b = blockIdx.x;
  int chunk = b & 15, cog = (b >> 4) & 15, n = b >> 8;
  int t = threadIdx.x;
  int wo = t & 63, ho = chunk * 4 + (t >> 6);
  int co0 = cog * 8;
  const float* xb = h1p + (size_t)n * 128 * 16900 + (size_t)(2 * ho) * 130 + 2 * wo;
  double acc[8] = {0.0, 0.0, 0.0, 0.0, 0.0, 0.0, 0.0, 0.0};
  float xf[16];
#pragma unroll
  for (int kh = 0; kh < 4; ++kh)
#pragma unroll
    for (int kw = 0; kw < 4; ++kw) xf[kh * 4 + kw] = xb[kh * 130 + kw];
  for (int ci = 0; ci < 128; ++ci) {
    double xd[16];
#pragma unroll
    for (int tp = 0; tp < 16; ++tp) xd[tp] = (double)xf[tp];
    if (ci < 127) {
      const float* xn = xb + (size_t)(ci + 1) * 16900;
#pragma unroll
      for (int kh = 0; kh < 4; ++kh)
#pragma unroll
        for (int kw = 0; kw < 4; ++kw) xf[kh * 4 + kw] = xn[kh * 130 + kw];
    }
#pragma unroll
    for (int cc = 0; cc < 8; ++cc) {
      const double* wp = wd + (size_t)(co0 + cc) * 2048 + ci * 16;
#pragma unroll
      for (int tp = 0; tp < 16; ++tp)
        acc[cc] = fma(xd[tp], wp[tp], acc[cc]);
    }
  }
#pragma unroll
  for (int cc = 0; cc < 8; ++cc) {
    float r = (float)((double)bias[co0 + cc] + acc[cc]);
    h2p[(((size_t)n * 128 + co0 + cc) * 66 + ho + 1) * 66 + wo + 1] = fmaxf(r, 0.0f);
  }
}

// ---------- enc conv3: k=3 s=1 (no relu), co x8, f64 w, x prefetch ----------
__global__ __launch_bounds__(256) void conv3_k(
    const float* __restrict__ h2p, const double* __restrict__ wd,
    const float* __restrict__ bias, float* __restrict__ h3) {
  int b = blockIdx.x;
  int chunk = b & 15, cog = (b >> 4) & 15, n = b >> 8;
  int t = threadIdx.x;
  int wo = t & 63, ho = chunk * 4 + (t >> 6);
  int co0 = cog * 8;
  const float* xb = h2p + (size_t)n * 128 * 4356 + (size_t)ho * 66 + wo;
  double acc[8] = {0.0, 0.0, 0.0, 0.0, 0.0, 0.0, 0.0, 0.0};
  float xf[9];
#pragma unroll
  for (int kh = 0; kh < 3; ++kh)
#pragma unroll
    for (int kw = 0; kw < 3; ++kw) xf[kh * 3 + kw] = xb[kh * 66 + kw];
  for (int ci = 0; ci < 128; ++ci) {
    double xd[9];
#pragma unroll
    for (int tp = 0; tp < 9; ++tp) xd[tp] = (double)xf[tp];
    if (ci < 127) {
      const float* xn = xb + (size_t)(ci + 1) * 4356;
#pragma unroll
      for (int kh = 0; kh < 3; ++kh)
#pragma unroll
        for (int kw = 0; kw < 3; ++kw) xf[kh * 3 + kw] = xn[kh * 66 + kw];
    }
#pragma unroll
    for (int cc = 0; cc < 8; ++cc) {
      const double* wp = wd + (size_t)(co0 + cc) * 1152 + ci * 9;
#pragma unroll
      for (int tp = 0; tp < 9; ++tp)
        acc[cc] = fma(xd[tp], wp[tp], acc[cc]);
    }
  }
#pragma unroll
  for (int cc = 0; cc < 8; ++cc)
    h3[(((size_t)n * 128 + co0 + cc) << 12) + (ho << 6) + wo] =
        (float)((double)bias[co0 + cc] + acc[cc]);
}

// ---------- 1x1 conv 128->256 fused: zf + Ap(f16) + znorm ----------
__global__ __launch_bounds__(256) void qconv_z_k(
    const float* __restrict__ h3, const float* __restrict__ wT,
    const float* __restrict__ bias, float* __restrict__ zf,
    _Float16* __restrict__ Ap, float* __restrict__ znb) {
  __shared__ double wsum[4];
  int p  = blockIdx.x;
  int co = threadIdx.x;
  int n  = p >> 12;
  int hw = p & 4095;
  const float* xp = h3 + ((size_t)n * 128) * 4096 + hw;
  double a[4] = {0.0, 0.0, 0.0, 0.0};
  for (int ci = 0; ci < 128; ci += 4) {
#pragma unroll
    for (int u = 0; u < 4; ++u) {
      float xv = xp[(size_t)(ci + u) * 4096];
      a[u] = fma((double)xv, (double)wT[(size_t)(ci + u) * 256 + co], a[u]);
    }
  }
  double acc = (double)bias[co] + ((a[0] + a[1]) + (a[2] + a[3]));
  float zv = (float)acc;
  zf[(size_t)p * 256 + co] = zv;
  Ap[(size_t)p * 256 + co] = (_Float16)zv;
  float xx = zv * zv;
  double s = (double)xx;
#pragma unroll
  for (int off = 32; off > 0; off >>= 1) s += __shfl_down(s, off, 64);
  if ((co & 63) == 0) wsum[co >> 6] = s;
  __syncthreads();
  if (co == 0) znb[p] = (float)((wsum[0] + wsum[1]) + (wsum[2] + wsum[3]));
}

// ---------- codebook prep fused: Bp(f16 x512) + cnorm ----------
__global__ __launch_bounds__(256) void cbprep_k(
    const float* __restrict__ cb, _Float16* __restrict__ Bp,
    float* __restrict__ cnb) {
  __shared__ double wsum[4];
  int k = blockIdx.x, t = threadIdx.x;
  float c = cb[(size_t)k * 256 + t];
  Bp[(size_t)k * 256 + t] = (_Float16)(c * 512.0f);
  float xx = c * c;
  double s = (double)xx;
#pragma unroll
  for (int off = 32; off > 0; off >>= 1) s += __shfl_down(s, off, 64);
  if ((t & 63) == 0) wsum[t >> 6] = s;
  __syncthreads();
  if (t == 0) cnb[k] = (float)((wsum[0] + wsum[1]) + (wsum[2] + wsum[3]));
}

// ---------- VQ filter GEMM: 128x128 tile, 16x16x32 f16 MFMA, K=256 ----------
__global__ __launch_bounds__(256, 2) void vq_gemm_k(
    const _Float16* __restrict__ Ah, const _Float16* __restrict__ Bh,
    const float* __restrict__ cnArr, int4* __restrict__ binfo) {
  __shared__ __align__(16) _Float16 As[128 * LDSS];
  __shared__ __align__(16) _Float16 Bs[128 * LDSS];
  __shared__ unsigned loc[128];
  __shared__ int cnt_sh[128];
  __shared__ int cand_sh[128][2];
  const int t = threadIdx.x;
  const int w = t >> 6, L = t & 63;
  const int mb = blockIdx.x >> 6;
  const int nb = blockIdx.x & 63;
  const int m0 = mb << 7, n0 = nb << 7;
  if (t < 128) { loc[t] = 0xFFFFFFFFu; cnt_sh[t] = 0; }
  f32x4 acc[4][4] = {};
  const int wr = (w >> 1) << 6, wc = (w & 1) << 6;
  const int srow = L >> 2, kg = L & 3;
  const int q = L >> 4, ln = L & 15;
  for (int kk = 0; kk < 256; kk += 32) {
    __syncthreads();
#pragma unroll
    for (int c = 0; c < 2; ++c) {
      const int row = (w << 5) + (c << 4) + srow;
      const f16x8 av = *(const f16x8*)(Ah + (size_t)(m0 + row) * 256 + kk + kg * 8);
      *(f16x8*)(&As[row * LDSS + kg * 8]) = av;
      const f16x8 bv = *(const f16x8*)(Bh + (size_t)(n0 + row) * 256 + kk + kg * 8);
      *(f16x8*)(&Bs[row * LDSS + kg * 8]) = bv;
    }
    __syncthreads();
    f16x8 af[4], bf[4];
#pragma unroll
    for (int i = 0; i < 4; ++i)
      af[i] = *(const f16x8*)(&As[(wr + 16 * i + ln) * LDSS + q * 8]);
#pragma unroll
    for (int j = 0; j < 4; ++j)
      bf[j] = *(const f16x8*)(&Bs[(wc + 16 * j + ln) * LDSS + q * 8]);
#pragma unroll
    for (int i = 0; i < 4; ++i)
#pragma unroll
      for (int j = 0; j < 4; ++j)
        acc[i][j] = __builtin_amdgcn_mfma_f32_16x16x32_f16(af[i], bf[j], acc[i][j], 0, 0, 0);
  }
  float cnv[4];
#pragma unroll
  for (int j = 0; j < 4; ++j) cnv[j] = cnArr[n0 + wc + 16 * j + ln];
#pragma unroll
  for (int i = 0; i < 4; ++i)
#pragma unroll
    for (int r = 0; r < 4; ++r) {
      float mn = 3.4e38f;
#pragma unroll
      for (int j = 0; j < 4; ++j)
        mn = fminf(mn, fmaf(-0.00390625f, acc[i][j][r], cnv[j]));
      atomicMin(&loc[wr + 16 * i + 4 * q + r], fkey(mn));
    }
  __syncthreads();
#pragma unroll
  for (int i = 0; i < 4; ++i)
#pragma unroll
    for (int r = 0; r < 4; ++r) {
      const int rib = wr + 16 * i + 4 * q + r;
      const float thr = funkey(loc[rib]) + VQ_MARGIN;
#pragma unroll
      for (int j = 0; j < 4; ++j) {
        float s = fmaf(-0.00390625f, acc[i][j][r], cnv[j]);
        if (s <= thr) {
          int slot = atomicAdd(&cnt_sh[rib], 1);
          if (slot < 2) cand_sh[rib][slot] = n0 + wc + 16 * j + ln;
        }
      }
    }
  __syncthreads();
  if (t < 128) {
    int4 v;
    v.x = cnt_sh[t];
    v.y = cand_sh[t][0];
    v.z = cand_sh[t][1];
    v.w = (int)__float_as_uint(funkey(loc[t]));
    binfo[(size_t)(m0 + t) * 64 + nb] = v;
  }
}

// ---------- VQ final: binfo-pruned argmin (also zeroes accum for commit) ----------
__global__ __launch_bounds__(256) void vq_phase3_k(
    const float* __restrict__ zf, const float* __restrict__ cb,
    const float* __restrict__ znArr, const float* __restrict__ cnArr,
    const int4* __restrict__ binfo, int* __restrict__ idxOut,
    float* __restrict__ accum) {
  if (blockIdx.x == 0 && threadIdx.x == 0) *accum = 0.0f;
  const int lane = threadIdx.x & 63;
  const int r = blockIdx.x * 4 + (threadIdx.x >> 6);
  const float* zr = zf + (size_t)r * 256;
  double z4[4];
#pragma unroll
  for (int j = 0; j < 4; ++j) z4[j] = (double)zr[lane + (j << 6)];
  const float znr = znArr[r];
  int4 b = binfo[(size_t)r * 64 + lane];
  float bv = __uint_as_float((unsigned)b.w);
  float m = bv;
#pragma unroll
  for (int off = 32; off > 0; off >>= 1) m = fminf(m, __shfl_down(m, off, 64));
  m = __shfl(m, 0, 64);
  const float thr = m + VQ_MARGIN;
  unsigned long long mask = __ballot(bv <= thr);
  float bestd = 3.4e38f;
  int bestk = 0x7fffffff;
  while (mask) {
    const int nb = (int)__builtin_ctzll(mask);
    mask &= mask - 1;
    const int c  = __shfl(b.x, nb, 64);
    const int k0 = __shfl(b.y, nb, 64);
    const int k1 = __shfl(b.z, nb, 64);
    const int nsc = (c <= 2) ? c : 128;
    for (int s2 = 0; s2 < nsc; ++s2) {
      const int k = (c <= 2) ? (s2 == 0 ? k0 : k1) : (nb * 128 + s2);
      const float* ck = cb + (size_t)k * 256;
      double p = 0.0;
#pragma unroll
      for (int j = 0; j < 4; ++j)
        p = fma(z4[j], (double)ck[lane + (j << 6)], p);
#pragma unroll
      for (int off = 32; off > 0; off >>= 1) p += __shfl_down(p, off, 64);
      if (lane == 0) {
        float mm2 = (float)(2.0 * p);
        float t1 = znr + cnArr[k];
        float d = t1 - mm2;
        if (d < bestd || (d == bestd && k < bestk)) { bestd = d; bestk = k; }
      }
    }
  }
  if (lane == 0) idxOut[r] = bestk;
}

// ---------- commit loss partials + indices-as-float output ----------
__global__ __launch_bounds__(256) void commit_k(
    const float* __restrict__ zf, const float* __restrict__ cb,
    const int* __restrict__ idxArr, float* __restrict__ accum,
    float* __restrict__ outIdxF) {
  __shared__ float wsum[4];
  const int p = blockIdx.x;
  const int t = threadIdx.x;
  const int k = idxArr[p];
  float d = cb[(size_t)k * 256 + t] - zf[(size_t)p * 256 + t];
  float v = d * d;
#pragma unroll
  for (int off = 32; off > 0; off >>= 1) v += __shfl_down(v, off, 64);
  if ((t & 63) == 0) wsum[t >> 6] = v;
  __syncthreads();
  if (t == 0) {
    atomicAdd(accum, wsum[0] + wsum[1] + wsum[2] + wsum[3]);
    outIdxF[p] = (float)k;
  }
}

// ---------- projected codebook PC[k][co] = sum_ci cb[k][ci]*pw[co][ci] ----------
__global__ __launch_bounds__(256) void pc_k(const float* __restrict__ cb,
                                            const float* __restrict__ pw,
                                            float* __restrict__ PC) {
  int tid = blockIdx.x * 256 + threadIdx.x;
  int co = tid & 127, k = tid >> 7;
  const float* c = cb + (size_t)k * 256;
  const float* w = pw + (size_t)co * 256;
  float a0 = 0.0f, a1 = 0.0f, a2 = 0.0f, a3 = 0.0f;
  for (int ci = 0; ci < 256; ci += 4) {
    a0 = fmaf(c[ci], w[ci], a0);
    a1 = fmaf(c[ci + 1], w[ci + 1], a1);
    a2 = fmaf(c[ci + 2], w[ci + 2], a2);
    a3 = fmaf(c[ci + 3], w[ci + 3], a3);
  }
  PC[tid] = (a0 + a1) + (a2 + a3);
}

// ---------- decoder pad zeros (qbufp, d1p: 66; d2p: 130) ----------
__global__ __launch_bounds__(256) void padzero_dec_k(
    float* __restrict__ qbufp, float* __restrict__ d1p, float* __restrict__ d2p) {
  int b = blockIdx.x, t = threadIdx.x;
  if (b < 512)       padzero_img(qbufp + (size_t)b * 4356, 66, t);
  else if (b < 1024) padzero_img(d1p + (size_t)(b - 512) * 4356, 66, t);
  else               padzero_img(d2p + (size_t)(b - 1024) * 16900, 130, t);
}

// ---------- q = gather(PC, idx) + bias, padded NCHW [66][66] ----------
__global__ __launch_bounds__(256) void gather_pc_k(
    const float* __restrict__ PC, const int* __restrict__ idxArr,
    const float* __restrict__ pb, float* __restrict__ qp) {
  int tid = blockIdx.x * 256 + threadIdx.x;
  int hw = tid & 4095;
  int co = (tid >> 12) & 127;
  int n  = tid >> 19;
  int p  = (n << 12) + hw;
  int h = hw >> 6, w2 = hw & 63;
  qp[(((size_t)n * 128 + co) * 66 + h + 1) * 66 + w2 + 1] =
      PC[(size_t)idxArr[p] * 128 + co] + pb[co];
}

// ---------- dec conv1: fp32 k=3 s=1 + relu, co x4 ----------
__global__ __launch_bounds__(256) void dconv1_k(
    const float* __restrict__ qp, const float* __restrict__ w,
    const float* __restrict__ bias, float* __restrict__ d1p) {
  int b = blockIdx.x;
  int chunk = b & 15, cog = (b >> 4) & 31, n = b >> 9;
  int t = threadIdx.x;
  int wo = t & 63, ho = chunk * 4 + (t >> 6);
  int co0 = cog * 4;
  const float* xb = qp + (size_t)n * 128 * 4356 + (size_t)ho * 66 + wo;
  float acc[4] = {0.0f, 0.0f, 0.0f, 0.0f};
  for (int ci = 0; ci < 128; ++ci) {
    const float* xc = xb + (size_t)ci * 4356;
    float xv[9];
#pragma unroll
    for (int kh = 0; kh < 3; ++kh)
#pragma unroll
      for (int kw = 0; kw < 3; ++kw) xv[kh * 3 + kw] = xc[kh * 66 + kw];
#pragma unroll
    for (int cc = 0; cc < 4; ++cc) {
      const float* wp = w + (size_t)(co0 + cc) * 1152 + ci * 9;
#pragma unroll
      for (int tp = 0; tp < 9; ++tp)
        acc[cc] = fmaf(xv[tp], wp[tp], acc[cc]);
    }
  }
#pragma unroll
  for (int cc = 0; cc < 4; ++cc)
    d1p[(((size_t)n * 128 + co0 + cc) * 66 + ho + 1) * 66 + wo + 1] =
        fmaxf(bias[co0 + cc] + acc[cc], 0.0f);
}

// ---------- convt2: parity-specialized, co x4, in d1p[66], out d2p[130] ----------
__global__ __launch_bounds__(256) void convt2_k(
    const float* __restrict__ xp, const float* __restrict__ wr,
    const float* __restrict__ bias, float* __restrict__ y) {
  int b = blockIdx.x;
  int chunk = b & 15, cls = (b >> 4) & 3, cog = (b >> 6) & 31, n = b >> 11;
  int cph = cls >> 1, cpw = cls & 1;
  int t = threadIdx.x;
  int wb = t & 63, i = chunk * 4 + (t >> 6);
  int co0 = cog * 4;
  int ho = 2 * i + cph, wo = 2 * wb + cpw;
  int r0 = i + 1 + cph, r1 = r0 - 1;
  int c0 = wb + 1 + cpw, c1 = c0 - 1;
  const float* xb = xp + (size_t)n * 128 * 4356;
  float acc[4] = {0.0f, 0.0f, 0.0f, 0.0f};
  for (int ci = 0; ci < 128; ++ci) {
    const float* xc = xb + (size_t)ci * 4356;
    float x00 = xc[r0 * 66 + c0], x01 = xc[r0 * 66 + c1];
    float x10 = xc[r1 * 66 + c0], x11 = xc[r1 * 66 + c1];
#pragma unroll
    for (int cc = 0; cc < 4; ++cc) {
      const float* w4 = wr + (((size_t)cls * 128 + co0 + cc) * 128 + ci) * 4;
      acc[cc] = fmaf(x00, w4[0], acc[cc]);
      acc[cc] = fmaf(x01, w4[1], acc[cc]);
      acc[cc] = fmaf(x10, w4[2], acc[cc]);
      acc[cc] = fmaf(x11, w4[3], acc[cc]);
    }
  }
#pragma unroll
  for (int cc = 0; cc < 4; ++cc)
    y[(((size_t)n * 128 + co0 + cc) * 130 + ho + 1) * 130 + wo + 1] =
        fmaxf(bias[co0 + cc] + acc[cc], 0.0f);
}

// ---------- convt3: parity-specialized, 3 co/thread (+ commit-loss finalize) ----------
__global__ __launch_bounds__(256) void convt3_k(
    const float* __restrict__ xp, const float* __restrict__ wr,
    const float* __restrict__ bias, float* __restrict__ y,
    const float* __restrict__ accum, float* __restrict__ outLoss) {
  int b = blockIdx.x;
  if (b == 0 && threadIdx.x == 0) *outLoss = *accum * (1.0f / 4194304.0f);
  int chunk = b & 63, cls = (b >> 6) & 3, n = b >> 8;
  int cph = cls >> 1, cpw = cls & 1;
  int t = threadIdx.x;
  int wb = t & 127, i = chunk * 2 + (t >> 7);
  int ho = 2 * i + cph, wo = 2 * wb + cpw;
  int r0 = i + 1 + cph, r1 = r0 - 1;
  int c0 = wb + 1 + cpw, c1 = c0 - 1;
  const float* xb = xp + (size_t)n * 128 * 16900;
  float acc[3] = {0.0f, 0.0f, 0.0f};
  for (int ci = 0; ci < 128; ++ci) {
    const float* xc = xb + (size_t)ci * 16900;
    float x00 = xc[r0 * 130 + c0], x01 = xc[r0 * 130 + c1];
    float x10 = xc[r1 * 130 + c0], x11 = xc[r1 * 130 + c1];
#pragma unroll
    for (int cc = 0; cc < 3; ++cc) {
      const float* w4 = wr + (((size_t)cls * 3 + cc) * 128 + ci) * 4;
      acc[cc] = fmaf(x00, w4[0], acc[cc]);
      acc[cc] = fmaf(x01, w4[1], acc[cc]);
      acc[cc] = fmaf(x10, w4[2], acc[cc]);
      acc[cc] = fmaf(x11, w4[3], acc[cc]);
    }
  }
#pragma unroll
  for (int cc = 0; cc < 3; ++cc)
    y[(((size_t)n * 3 + cc) << 16) + (ho << 8) + wo] = bias[cc] + acc[cc];
}

// ---------------------------------------------------------------------------
extern "C" void kernel_launch(void* const* d_in, const int* in_sizes, int n_in,
                              void* d_out, int out_size, void* d_ws, size_t ws_size,
                              hipStream_t stream) {
  const float* x    = (const float*)d_in[0];
  const float* ew1  = (const float*)d_in[1];
  const float* eb1  = (const float*)d_in[2];
  const float* ew2  = (const float*)d_in[3];
  const float* eb2  = (const float*)d_in[4];
  const float* ew3  = (const float*)d_in[5];
  const float* eb3  = (const float*)d_in[6];
  const float* qw   = (const float*)d_in[7];
  const float* qb   = (const float*)d_in[8];
  const float* cb   = (const float*)d_in[9];
  const float* pw   = (const float*)d_in[10];
  const float* pb   = (const float*)d_in[11];
  const float* dw1  = (const float*)d_in[12];
  const float* db1  = (const float*)d_in[13];
  const float* dtw2 = (const float*)d_in[14];
  const float* dtb2 = (const float*)d_in[15];
  const float* dtw3 = (const float*)d_in[16];
  const float* dtb3 = (const float*)d_in[17];

  char* wsb = (char*)d_ws;
  float*    h1p  = (float*)(wsb + OFF_A);
  _Float16* Ap   = (_Float16*)(wsb + OFF_A);
  int4*     binfo= (int4*)(wsb + OFF_BINFO);
  float*    d2p  = (float*)(wsb + OFF_A);
  float*    h2p  = (float*)(wsb + OFF_B);
  float*    qbufp= (float*)(wsb + OFF_B);
  float*    xpad = (float*)(wsb + OFF_C);
  float*    h3   = (float*)(wsb + OFF_C);
  float*    d1p  = (float*)(wsb + OFF_C);
  float*    zff  = (float*)(wsb + OFF_D);
  _Float16* Bp   = (_Float16*)(wsb + OFF_E);
  float*    PC   = (float*)(wsb + OFF_E);
  float*    znb  = (float*)(wsb + OFF_ZN);
  float*    cnb  = (float*)(wsb + OFF_CN);
  int*      idxb = (int*)(wsb + OFF_IDX);
  float*    accum= (float*)(wsb + OFF_ACC);
  float*    wr2  = (float*)(wsb + OFF_WR2);
  float*    wr3  = (float*)(wsb + OFF_WR3);
  float*    qwT  = (float*)(wsb + OFF_QWT);
  double*   wd2  = (double*)(wsb + OFF_WD2);
  double*   wd3  = (double*)(wsb + OFF_WD3);
  double*   wd1  = (double*)(wsb + OFF_WD1);

  float* out      = (float*)d_out;
  float* outLoss  = out + 786432;
  float* outIdxF  = out + 786433;

  hipLaunchKernelGGL(prep_k, dim3(3050), dim3(256), 0, stream,
                     dtw2, wr2, dtw3, wr3, qw, qwT, ew2, wd2, ew3, wd3,
                     ew1, wd1, xpad, h1p, h2p);

  // encoder: per-op fp32-rounded (f64-exact inside each op)
  hipLaunchKernelGGL(padx_k,    dim3(3072),  dim3(256), 0, stream, x, xpad);
  hipLaunchKernelGGL(conv1_k,   dim3(8192),  dim3(256), 0, stream, xpad, wd1, eb1, h1p);
  hipLaunchKernelGGL(conv2_k,   dim3(1024),  dim3(256), 0, stream, h1p, wd2, eb2, h2p);
  hipLaunchKernelGGL(conv3_k,   dim3(1024),  dim3(256), 0, stream, h2p, wd3, eb3, h3);
  hipLaunchKernelGGL(qconv_z_k, dim3(16384), dim3(256), 0, stream, h3, qwT, qb, zff, Ap, znb);

  // VQ: fp16 K=256 MFMA filter + binfo-pruned exact rescore
  hipLaunchKernelGGL(cbprep_k,    dim3(8192),  dim3(256), 0, stream, cb, Bp, cnb);
  hipLaunchKernelGGL(vq_gemm_k,   dim3(8192),  dim3(256), 0, stream, Ap, Bp, cnb, binfo);
  hipLaunchKernelGGL(vq_phase3_k, dim3(4096),  dim3(256), 0, stream, zff, cb, znb, cnb, binfo, idxb, accum);
  hipLaunchKernelGGL(commit_k,    dim3(16384), dim3(256), 0, stream, zff, cb, idxb, accum, outIdxF);

  // decoder fp32 (pqconv folded through codebook: q = PC[idx] + b)
  hipLaunchKernelGGL(pc_k,          dim3(4096), dim3(256), 0, stream, cb, pw, PC);
  hipLaunchKernelGGL(padzero_dec_k, dim3(1536), dim3(256), 0, stream, qbufp, d1p, d2p);
  hipLaunchKernelGGL(gather_pc_k,   dim3(8192), dim3(256), 0, stream, PC, idxb, pb, qbufp);
  hipLaunchKernelGGL(dconv1_k,      dim3(2048), dim3(256), 0, stream, qbufp, dw1, db1, d1p);
  hipLaunchKernelGGL(convt2_k,      dim3(8192), dim3(256), 0, stream, d1p, wr2, dtb2, d2p);
  hipLaunchKernelGGL(convt3_k,      dim3(1024), dim3(256), 0, stream, d2p, wr3, dtb3, out, accum, outLoss);
}